// Round 1
// 615.391 us; speedup vs baseline: 1.0357x; 1.0357x over previous
//
#include <hip/hip_runtime.h>
#include <hip/hip_bf16.h>

// Bahdanau attention, MI355X. B=32, T=2048, D=1024, U=1024.
// R4: score GEMM ported from the m97-class 128^2 2-barrier structure (654 TF,
// MfmaUtil 28%, 1.7e7 LDS bank conflicts) to the 8-phase 256^2 template:
//   - 256x256 tile, BK=64, 8 waves (2Mx4N), 128 KiB LDS double-buffer, 1 blk/CU
//   - XOR swizzle byte^=((row&7)<<4): pre-swizzled global src + swizzled ds_read
//   - asm ds_read_b128 + lgkmcnt(0) + sched_barrier(0) (defeats LLVM LDS-DMA
//     auto-vmcnt(0)); counted vmcnt(4) once per K-tile, never 0 in steady loop
//   - setprio(1) around each 16-MFMA cluster; XCD-aware block swizzle kept.

typedef __bf16 bf16x8 __attribute__((ext_vector_type(8)));
typedef __bf16 bf16x4 __attribute__((ext_vector_type(4)));
typedef short  s16x8  __attribute__((ext_vector_type(8)));
typedef float  f32x4  __attribute__((ext_vector_type(4)));

#define B_  32
#define T_  2048
#define D_  1024
#define U_  1024
#define BT_ (B_*T_)

// ws layout (bytes)
#define WS_W1T    ((size_t)0)                          // 2 MiB bf16 [U][D]
#define WS_PROJQ  ((size_t)(2u*1024*1024))             // 128 KiB fp32 [B][U]
#define WS_SCORE  ((size_t)(2u*1024*1024 + 128u*1024)) // 256 KiB fp32 [B*T]
#define WS_VALB   ((size_t)(4u*1024*1024))             // 128 MiB bf16 [BT][D]
#define WS_NEEDED (WS_VALB + (size_t)BT_ * D_ * 2)

__device__ __forceinline__ float tanh_fast(float x) {
    const float e = __expf(2.0f * x);
    return 1.0f - __fdividef(2.0f, e + 1.0f);
}

__device__ __forceinline__ void glls16(const void* g, void* l) {
    __builtin_amdgcn_global_load_lds(
        (const __attribute__((address_space(1))) void*)g,
        (__attribute__((address_space(3))) void*)l, 16, 0, 0);
}

// ---------------- init: projq = b1+b2 (broadcast), score = 0 ----------------
__global__ void init_kernel(const float* __restrict__ b1, const float* __restrict__ b2,
                            float* __restrict__ projq, float* __restrict__ score) {
    int i = blockIdx.x * 256 + threadIdx.x;       // grid 384*256 = 98304 exact
    if (i < B_ * U_) {
        projq[i] = b1[i & (U_ - 1)] + b2[i & (U_ - 1)];
    } else {
        score[i - B_ * U_] = 0.0f;
    }
}

// ---------------- values fp32 -> bf16 (streaming) ----------------
__global__ void convert_kernel(const float* __restrict__ v, __bf16* __restrict__ o) {
    const size_t i = ((size_t)blockIdx.x * 256 + threadIdx.x) * 8;   // grid 32768
    const float4 a = *(const float4*)(v + i);
    const float4 b = *(const float4*)(v + i + 4);
    bf16x8 h;
    h[0] = (__bf16)a.x; h[1] = (__bf16)a.y; h[2] = (__bf16)a.z; h[3] = (__bf16)a.w;
    h[4] = (__bf16)b.x; h[5] = (__bf16)b.y; h[6] = (__bf16)b.z; h[7] = (__bf16)b.w;
    *(bf16x8*)(o + i) = h;
}

// ---------------- W1 [D][U] fp32 -> W1T [U][D] bf16 ----------------
__global__ void w1_transpose_kernel(const float* __restrict__ W1, __bf16* __restrict__ W1T) {
    __shared__ float tile[64][65];
    const int bx = blockIdx.x & 15;   // u tile
    const int by = blockIdx.x >> 4;   // d tile
    const int tid = threadIdx.x;      // 256
    const int j  = tid & 63;
    const int i0 = tid >> 6;          // 0..3
#pragma unroll
    for (int p = 0; p < 16; ++p) {
        const int i = i0 + p * 4;
        tile[i][j] = W1[(size_t)(by * 64 + i) * U_ + bx * 64 + j];
    }
    __syncthreads();
#pragma unroll
    for (int p = 0; p < 16; ++p) {
        const int i = i0 + p * 4;     // local u row
        W1T[(size_t)(bx * 64 + i) * D_ + by * 64 + j] = (__bf16)tile[j][i];
    }
}

// ---------------- projq += query @ W2 (fp32, d-split + atomics) ----------------
__global__ void projq_kernel(const float* __restrict__ query, const float* __restrict__ W2,
                             float* __restrict__ projq) {
    __shared__ float q[128];
    const int b  = blockIdx.x >> 3;   // 32
    const int dc = blockIdx.x & 7;    // 8 chunks of 128 d
    const int tid = threadIdx.x;      // 256
    if (tid < 128) q[tid] = query[(size_t)b * D_ + dc * 128 + tid];
    __syncthreads();
    const int u0 = tid * 4;
    float a0 = 0.f, a1 = 0.f, a2 = 0.f, a3 = 0.f;
    for (int d = 0; d < 128; ++d) {
        const float4 w = *(const float4*)(W2 + (size_t)(dc * 128 + d) * U_ + u0);
        const float qd = q[d];
        a0 = fmaf(qd, w.x, a0); a1 = fmaf(qd, w.y, a1);
        a2 = fmaf(qd, w.z, a2); a3 = fmaf(qd, w.w, a3);
    }
    float* p = projq + (size_t)b * U_ + u0;
    atomicAdd(p + 0, a0); atomicAdd(p + 1, a1);
    atomicAdd(p + 2, a2); atomicAdd(p + 3, a3);
}

// ---------------- fused score GEMM: 8-phase 256^2 template ----------------
// Grid 1024 = 256 mblk x 4 nblk, XCD-swizzled so the 4 nblks sharing an
// A-rowpanel are co-XCD and temporally adjacent. 512 threads = 8 waves
// (2M x 4N); wave output 128x64. LDS: 2 buffers x {A 256x64, B 256x64} bf16
// = 128 KiB, each tile stored as 2 halves of [128][64] with XOR swizzle
// byte ^= ((row&7)<<4) (linear gload_lds dest + inverse-swizzled global src
// + swizzled ds_read — same involution both sides).
//
// Staging schedule per K-tile t (buf c = t&1): ph0: A(t+1)h0 -> buf c^1;
// ph1: A(t+1)h1 -> c^1; ph2: B(t+2)h0 -> c; ph3: B(t+2)h1 -> c. Region-retire
// proof: B(t) reads drain by ph1's lgkmcnt+barrier; A(t) reads by ph2's.
// vmcnt(4) at ph3 leaves exactly B(t+2)'s 4 loads in flight and guarantees
// A(t+1) and B(t+1) landed before the t+1 ph0 ds_reads.

#define SC_LDSB 32768   // elements per LDS buffer (64 KiB); A at +0, B at +16384

__global__ __launch_bounds__(512, 2)
void score_kernel_8ph(const __bf16* __restrict__ valb, const __bf16* __restrict__ W1T,
                      const float* __restrict__ projq, const float* __restrict__ V,
                      float* __restrict__ score) {
    __shared__ __attribute__((aligned(16))) __bf16 lds[2 * SC_LDSB];  // 128 KiB

    const int tid  = threadIdx.x;
    const int bid  = blockIdx.x;
    const int xcd  = bid & 7;
    const int sl   = bid >> 3;            // 0..127
    const int mblk = xcd * 32 + (sl >> 2);
    const int nblk = sl & 3;

    const int wv   = tid >> 6;            // wave 0..7
    const int lane = tid & 63;
    const int wm   = wv >> 2;             // 0..1 : A half
    const int wn   = wv & 3;              // 0..3 : 64-col slice of B
    const int l15  = lane & 15, quad = lane >> 4;
    const int e    = l15 & 7;
    const int sl0  = ((quad)     ^ e) * 8;   // swizzled slot, kstep 0
    const int sl1  = ((quad + 4) ^ e) * 8;   // swizzled slot, kstep 1
    const int offA0 = wm * 8192 + l15 * 64 + sl0;
    const int offA1 = wm * 8192 + l15 * 64 + sl1;
    const int offB0 = 16384 + (wn >> 1) * 8192 + ((wn & 1) * 64 + l15) * 64 + sl0;
    const int offB1 = 16384 + (wn >> 1) * 8192 + ((wn & 1) * 64 + l15) * 64 + sl1;

    // staging: lane covers phys row (wv*8 + lane>>3), phys slot (lane&7);
    // logical (pre-swizzled) source slot = (lane&7) ^ (row&7)
    const int srow = lane >> 3;
    const int scol = ((lane & 7) ^ srow) * 8;
    const __bf16* aS = valb + ((size_t)mblk * 256 + wv * 8 + srow) * D_ + scol;
    const __bf16* bS = W1T  + ((size_t)nblk * 256 + wv * 8 + srow) * D_ + scol;
    __bf16* aD = lds + wv * 512;            // wave-uniform linear dest bases
    __bf16* bD = lds + 16384 + wv * 512;

#define DSR(dst, off) do { s16x8 _t;                                            \
    asm volatile("ds_read_b128 %0, %1" : "=v"(_t)                              \
        : "v"((const __attribute__((address_space(3))) __bf16*)(lds + (off)))); \
    (dst) = __builtin_bit_cast(bf16x8, _t); } while (0)

#define STA(CB, H, KT) do {                                                     \
    glls16(aS + (size_t)((H)*128     ) * D_ + (KT)*64, aD + (CB) + (H)*8192);        \
    glls16(aS + (size_t)((H)*128 + 64) * D_ + (KT)*64, aD + (CB) + (H)*8192 + 4096); \
    } while (0)
#define STB(CB, H, KT) do {                                                     \
    glls16(bS + (size_t)((H)*128     ) * D_ + (KT)*64, bD + (CB) + (H)*8192);        \
    glls16(bS + (size_t)((H)*128 + 64) * D_ + (KT)*64, bD + (CB) + (H)*8192 + 4096); \
    } while (0)

#define PH_SYNC do { __builtin_amdgcn_s_barrier();                              \
    asm volatile("s_waitcnt lgkmcnt(0)" ::: "memory");                          \
    __builtin_amdgcn_sched_barrier(0);                                          \
    __builtin_amdgcn_s_setprio(1); } while (0)
#define PH_END do { __builtin_amdgcn_s_setprio(0);                              \
    __builtin_amdgcn_s_barrier(); } while (0)

#define MQ(ML, NL) do {                                                         \
    _Pragma("unroll") for (int mi = 0; mi < 4; ++mi)                            \
    _Pragma("unroll") for (int ni = 0; ni < 2; ++ni) {                          \
        acc[(ML)+mi][(NL)+ni] = __builtin_amdgcn_mfma_f32_16x16x32_bf16(        \
            afr[mi][0], bfr[(NL)+ni][0], acc[(ML)+mi][(NL)+ni], 0, 0, 0);       \
        acc[(ML)+mi][(NL)+ni] = __builtin_amdgcn_mfma_f32_16x16x32_bf16(        \
            afr[mi][1], bfr[(NL)+ni][1], acc[(ML)+mi][(NL)+ni], 0, 0, 0);       \
    } } while (0)

#define TILE(KT, CB, DOA, DOB, VM) do {                                         \
    /* phase 0: a[0..3], b[0..1]; stage A(t+1)h0 */                             \
    _Pragma("unroll") for (int m = 0; m < 4; ++m) {                             \
        DSR(afr[m][0], (CB) + offA0 + m*1024);                                  \
        DSR(afr[m][1], (CB) + offA1 + m*1024); }                                \
    _Pragma("unroll") for (int n = 0; n < 2; ++n) {                             \
        DSR(bfr[n][0], (CB) + offB0 + n*1024);                                  \
        DSR(bfr[n][1], (CB) + offB1 + n*1024); }                                \
    if (DOA) STA((CB) ^ SC_LDSB, 0, (KT)+1);                                    \
    PH_SYNC; MQ(0, 0); PH_END;                                                  \
    /* phase 1: b[2..3]; stage A(t+1)h1 */                                      \
    _Pragma("unroll") for (int n = 0; n < 2; ++n) {                             \
        DSR(bfr[2+n][0], (CB) + offB0 + (2+n)*1024);                            \
        DSR(bfr[2+n][1], (CB) + offB1 + (2+n)*1024); }                          \
    if (DOA) STA((CB) ^ SC_LDSB, 1, (KT)+1);                                    \
    PH_SYNC; MQ(0, 2); PH_END;                                                  \
    /* phase 2: a[4..7]; stage B(t+2)h0 */                                      \
    _Pragma("unroll") for (int m = 0; m < 4; ++m) {                             \
        DSR(afr[m][0], (CB) + offA0 + (4+m)*1024);                              \
        DSR(afr[m][1], (CB) + offA1 + (4+m)*1024); }                            \
    if (DOB) STB((CB), 0, (KT)+2);                                              \
    PH_SYNC; MQ(4, 0); PH_END;                                                  \
    /* phase 3: stage B(t+2)h1; counted vmcnt before publish barrier */         \
    if (DOB) STB((CB), 1, (KT)+2);                                              \
    __builtin_amdgcn_s_barrier();                                               \
    __builtin_amdgcn_sched_barrier(0);                                          \
    __builtin_amdgcn_s_setprio(1);                                              \
    MQ(4, 2);                                                                   \
    __builtin_amdgcn_s_setprio(0);                                              \
    if ((VM) == 4)      asm volatile("s_waitcnt vmcnt(4)" ::: "memory");        \
    else if ((VM) == 0) asm volatile("s_waitcnt vmcnt(0)" ::: "memory");        \
    __builtin_amdgcn_s_barrier();                                               \
} while (0)

    bf16x8 afr[4][2];
    bf16x8 bfr[4][2];
    f32x4  acc[8][4];
#pragma unroll
    for (int i = 0; i < 8; ++i)
#pragma unroll
        for (int j = 0; j < 4; ++j) { f32x4 z = {0.f, 0.f, 0.f, 0.f}; acc[i][j] = z; }

    // prologue: tile0 (A+B) -> buf0, tile1 B -> buf1; wait tile0 landed.
    STA(0, 0, 0); STA(0, 1, 0); STB(0, 0, 0); STB(0, 1, 0);
    STB(SC_LDSB, 0, 1); STB(SC_LDSB, 1, 1);
    asm volatile("s_waitcnt vmcnt(4)" ::: "memory");
    __builtin_amdgcn_s_barrier();

#pragma unroll 1
    for (int tt = 0; tt < 14; tt += 2) {
        TILE(tt,     0,       1, 1, 4);
        TILE(tt + 1, SC_LDSB, 1, 1, 4);
    }
    TILE(14, 0,       1, 0, 0);    // stage A(15) only; drain
    TILE(15, SC_LDSB, 0, 0, -1);   // no staging, no wait

    // epilogue: partial score = sum_u tanh(acc + projq[b][u]) * V[u]
    const int bq = mblk >> 3;                  // 8 mblks (of 256 rows) per batch
    const float* pq = projq + (size_t)bq * U_ + nblk * 256 + wn * 64;
    const float* Vp = V + nblk * 256 + wn * 64;
    float pqu[4], vu[4];
#pragma unroll
    for (int nt = 0; nt < 4; ++nt) { pqu[nt] = pq[nt * 16 + l15]; vu[nt] = Vp[nt * 16 + l15]; }
    const size_t rowbase = (size_t)mblk * 256 + (size_t)wm * 128;
#pragma unroll
    for (int mt = 0; mt < 8; ++mt) {
        float s0 = 0.f, s1 = 0.f, s2 = 0.f, s3 = 0.f;
#pragma unroll
        for (int nt = 0; nt < 4; ++nt) {
            s0 += tanh_fast(acc[mt][nt][0] + pqu[nt]) * vu[nt];
            s1 += tanh_fast(acc[mt][nt][1] + pqu[nt]) * vu[nt];
            s2 += tanh_fast(acc[mt][nt][2] + pqu[nt]) * vu[nt];
            s3 += tanh_fast(acc[mt][nt][3] + pqu[nt]) * vu[nt];
        }
        float s[4] = {s0, s1, s2, s3};
#pragma unroll
        for (int r = 0; r < 4; ++r) {
            float v = s[r];
            v += __shfl_xor(v, 1);
            v += __shfl_xor(v, 2);
            v += __shfl_xor(v, 4);
            v += __shfl_xor(v, 8);
            if (l15 == 0)
                atomicAdd(&score[rowbase + mt * 16 + quad * 4 + r], v);
        }
    }
#undef DSR
#undef STA
#undef STB
#undef PH_SYNC
#undef PH_END
#undef MQ
#undef TILE
}

// ---------------- R1 fallback score GEMM (fp32 staging), if ws too small ----
__global__ __launch_bounds__(512, 2)
void score_kernel_f32(const float* __restrict__ values, const __bf16* __restrict__ W1T,
                      const float* __restrict__ projq, const float* __restrict__ V,
                      float* __restrict__ score) {
    __shared__ __attribute__((aligned(16))) __bf16 Al[64][40];
    __shared__ __attribute__((aligned(16))) __bf16 Bl[512][40];
    const int tid    = threadIdx.x;
    const int rowblk = blockIdx.x >> 1;
    const int nhalf  = blockIdx.x & 1;
    const int wave = tid >> 6, lane = tid & 63;
    const int quad = lane >> 4, l15 = lane & 15;
    const float*  Abase = values + (size_t)rowblk * 64 * D_;
    const __bf16* Bbase = W1T + (size_t)nhalf * 512 * D_;
    const int ar = tid >> 3, ac = (tid & 7) * 4;
    const int br = tid >> 2, bc = (tid & 3) * 8;
    f32x4 acc[4][4];
#pragma unroll
    for (int i = 0; i < 4; ++i)
#pragma unroll
        for (int j = 0; j < 4; ++j) { f32x4 z = {0.f,0.f,0.f,0.f}; acc[i][j] = z; }
    for (int kk = 0; kk < D_; kk += 32) {
        {
            const float4 v = *(const float4*)(Abase + (size_t)ar * D_ + kk + ac);
            bf16x4 h;
            h[0] = (__bf16)v.x; h[1] = (__bf16)v.y; h[2] = (__bf16)v.z; h[3] = (__bf16)v.w;
            *(bf16x4*)(&Al[ar][ac]) = h;
        }
#pragma unroll
        for (int p = 0; p < 4; ++p) {
            const int rr = p * 128 + br;
            const bf16x8 w = *(const bf16x8*)(Bbase + (size_t)rr * D_ + kk + bc);
            *(bf16x8*)(&Bl[rr][bc]) = w;
        }
        __syncthreads();
        bf16x8 af[4];
#pragma unroll
        for (int mt = 0; mt < 4; ++mt)
            af[mt] = *(const bf16x8*)(&Al[mt * 16 + l15][quad * 8]);
#pragma unroll
        for (int nt = 0; nt < 4; ++nt) {
            const bf16x8 bfr = *(const bf16x8*)(&Bl[wave * 64 + nt * 16 + l15][quad * 8]);
#pragma unroll
            for (int mt = 0; mt < 4; ++mt)
                acc[mt][nt] = __builtin_amdgcn_mfma_f32_16x16x32_bf16(af[mt], bfr, acc[mt][nt], 0, 0, 0);
        }
        __syncthreads();
    }
    const int b = rowblk >> 5;
    const size_t rowbase = (size_t)rowblk * 64;
    const float* pq = projq + (size_t)b * U_;
    const int ub = nhalf * 512 + wave * 64;
#pragma unroll
    for (int mt = 0; mt < 4; ++mt) {
        float s0 = 0.f, s1 = 0.f, s2 = 0.f, s3 = 0.f;
#pragma unroll
        for (int nt = 0; nt < 4; ++nt) {
            const int u = ub + nt * 16 + l15;
            const float pqu = pq[u];
            const float vu  = V[u];
            s0 += tanh_fast(acc[mt][nt][0] + pqu) * vu;
            s1 += tanh_fast(acc[mt][nt][1] + pqu) * vu;
            s2 += tanh_fast(acc[mt][nt][2] + pqu) * vu;
            s3 += tanh_fast(acc[mt][nt][3] + pqu) * vu;
        }
        float s[4] = {s0, s1, s2, s3};
#pragma unroll
        for (int r = 0; r < 4; ++r) {
            float v = s[r];
            v += __shfl_xor(v, 1);
            v += __shfl_xor(v, 2);
            v += __shfl_xor(v, 4);
            v += __shfl_xor(v, 8);
            if (l15 == 0)
                atomicAdd(&score[rowbase + mt * 16 + quad * 4 + r], v);
        }
    }
}

// ---------------- softmax over T (masked), writes attention weights ----------------
__global__ void softmax_kernel(const float* __restrict__ score, const float* __restrict__ mask,
                               const float* __restrict__ bV, float* __restrict__ out) {
    const int b = blockIdx.x;     // 32
    const int tid = threadIdx.x;  // 256
    const float bv = bV[0];
    float s[8];
    float lmax = -3.0e38f;
#pragma unroll
    for (int i = 0; i < 8; ++i) {
        const int t = tid + i * 256;
        const float v = score[(size_t)b * T_ + t] + bv + mask[(size_t)b * T_ + t] * (-1.0e9f);
        s[i] = v;
        lmax = fmaxf(lmax, v);
    }
#pragma unroll
    for (int m = 1; m < 64; m <<= 1) lmax = fmaxf(lmax, __shfl_xor(lmax, m));
    __shared__ float redm[4], reds[4];
    if ((tid & 63) == 0) redm[tid >> 6] = lmax;
    __syncthreads();
    const float M = fmaxf(fmaxf(redm[0], redm[1]), fmaxf(redm[2], redm[3]));
    float lsum = 0.f;
#pragma unroll
    for (int i = 0; i < 8; ++i) { s[i] = __expf(s[i] - M); lsum += s[i]; }
#pragma unroll
    for (int m = 1; m < 64; m <<= 1) lsum += __shfl_xor(lsum, m);
    if ((tid & 63) == 0) reds[tid >> 6] = lsum;
    __syncthreads();
    const float inv = 1.0f / (reds[0] + reds[1] + reds[2] + reds[3]);
#pragma unroll
    for (int i = 0; i < 8; ++i)
        out[(size_t)B_ * D_ + (size_t)b * T_ + tid + i * 256] = s[i] * inv;
}

// ---------------- context = sum_t attn[b,t] * values[b,t,:] ----------------
__global__ void context_kernel(const float* __restrict__ values, const float* __restrict__ attn,
                               float* __restrict__ out) {
    const int b  = blockIdx.x >> 4;   // 32
    const int dc = blockIdx.x & 15;   // 16 chunks of 64 d
    const int tid = threadIdx.x;      // 256
    __shared__ float a[T_];
#pragma unroll
    for (int i = 0; i < 8; ++i) a[tid + i * 256] = attn[(size_t)b * T_ + tid + i * 256];
    __syncthreads();
    const int dl = (tid & 15) * 4;    // 64 d per block, float4 per thread
    const int tg = tid >> 4;          // 0..15
    const float* vb = values + (size_t)b * T_ * D_ + dc * 64 + dl;
    f32x4 acc = {0.f, 0.f, 0.f, 0.f};
#pragma unroll 4
    for (int t = tg; t < T_; t += 16) {
        const float4 v = *(const float4*)(vb + (size_t)t * D_);
        const float w = a[t];
        acc[0] = fmaf(w, v.x, acc[0]);
        acc[1] = fmaf(w, v.y, acc[1]);
        acc[2] = fmaf(w, v.z, acc[2]);
        acc[3] = fmaf(w, v.w, acc[3]);
    }
    __shared__ __attribute__((aligned(16))) float red[16][64];
    *(f32x4*)(&red[tg][dl]) = acc;
    __syncthreads();
    if (tid < 64) {
        float s = 0.f;
#pragma unroll
        for (int g = 0; g < 16; ++g) s += red[g][tid];
        out[(size_t)b * D_ + dc * 64 + tid] = s;
    }
}

extern "C" void kernel_launch(void* const* d_in, const int* in_sizes, int n_in,
                              void* d_out, int out_size, void* d_ws, size_t ws_size,
                              hipStream_t stream) {
    const float* values = (const float*)d_in[0];
    const float* query  = (const float*)d_in[1];
    const float* mask   = (const float*)d_in[2];
    const float* W1     = (const float*)d_in[3];
    const float* b1     = (const float*)d_in[4];
    const float* W2     = (const float*)d_in[5];
    const float* b2     = (const float*)d_in[6];
    const float* V      = (const float*)d_in[7];
    const float* bV     = (const float*)d_in[8];
    float* out = (float*)d_out;

    char* ws = (char*)d_ws;
    __bf16* W1T   = (__bf16*)(ws + WS_W1T);
    float*  projq = (float*)(ws + WS_PROJQ);
    float*  score = (float*)(ws + WS_SCORE);
    __bf16* valb  = (__bf16*)(ws + WS_VALB);

    init_kernel<<<dim3(384), dim3(256), 0, stream>>>(b1, b2, projq, score);
    w1_transpose_kernel<<<dim3(256), dim3(256), 0, stream>>>(W1, W1T);
    projq_kernel<<<dim3(256), dim3(256), 0, stream>>>(query, W2, projq);
    if (ws_size >= WS_NEEDED) {
        convert_kernel<<<dim3(32768), dim3(256), 0, stream>>>(values, valb);
        score_kernel_8ph<<<dim3(1024), dim3(512), 0, stream>>>(valb, W1T, projq, V, score);
    } else {
        score_kernel_f32<<<dim3(2048), dim3(512), 0, stream>>>(values, W1T, projq, V, score);
    }
    softmax_kernel<<<dim3(32), dim3(256), 0, stream>>>(score, mask, bV, out);
    context_kernel<<<dim3(512), dim3(256), 0, stream>>>(values, out + B_ * D_, out);
}